// Round 10
// baseline (41.538 us; speedup 1.0000x reference)
//
#include <hip/hip_runtime.h>
#include <math.h>

#define HD 512
#define WD 512
#define NP 255            // patch grid = 255 x 255
#define LK 7225           // patches per kk group; 7225 = 85*85
#define BATCH 32
#define RB 85             // r's per chunk (765 ll = exactly 3 pi2-rows)
#define CH 85
#define NQ 4              // pj2-quarters per chunk
#define NTHR 256
#define IMR 7             // contiguous image rows staged: [6c, 6c+6]
#define TCOLS 176         // 160 quarter cols + 16-col wrap strip
#define TENF (IMR * TCOLS)        // 1232 floats per tensor (14784 B total LDS)
#define NF4 (3 * IMR * 44)        // 924 float4 stage ops
#define NWG (BATCH * CH * NQ)     // 10880 blocks (div by 8 -> clean XCD swizzle)

// Semantics (reference's flat reshape (b,9,L)->(b,L,9)):
//   l = kk*7225 + r ; (di,dj) = (kk/3, kk%3) fixed within a 9-group
//   k in 0..8: ll = 9r+k -> pixel (2*(ll/255)+di, 2*(ll%255)+dj)
//   argmin/argmax |a-c| (first-occurrence), s = c[argmin]+c[argmax]
//   broadcast to 2x2 (3x3 at edges) block of patch (l/255, l%255); row/col 511 = 0.
//
// R9 = R8 with pj2-QUARTER blocks: 14.8 KB LDS -> 8 blocks/CU, each compute
// lane owns exactly ONE (kk,m) group (27 LDS reads), all waves stage, ~3.1/4
// waves compute. Quarter q covers pj2 in [64q, 64q+64): per j-row segment
// m in [mstart(j,q), +7or8). Wrap groups (pj2>=247, q=3 only) read the
// appended left-edge strip at constant offset +386 (= 2*TCOLS + 34).

typedef const __attribute__((address_space(1))) void* gp1_t;
typedef __attribute__((address_space(3))) void* lp3_t;

__global__ __launch_bounds__(NTHR) void dc_pool_kernel(
    const float* __restrict__ anchor,
    const float* __restrict__ pos,
    const float* __restrict__ neg,
    float* __restrict__ out0,
    float* __restrict__ out1)
{
    __shared__ float lds[3 * TENF];   // A | P | N, each 7 rows x 176 cols

    // XCD-aware swizzle (bijective: NWG % 8 == 0); a chunk's 4 quarters and
    // neighbor chunks land on the same XCD (consecutive vid = bids 8 apart).
    int bid = blockIdx.x;
    int vid = (bid & 7) * (NWG / 8) + (bid >> 3);
    int q     = vid & 3;
    int rest  = vid >> 2;
    int chunk = rest % CH;
    int b     = rest / CH;

    const size_t plane = (size_t)HD * WD;
    const float* A = anchor + (size_t)b * plane;
    const float* P = pos    + (size_t)b * plane;
    const float* N = neg    + (size_t)b * plane;
    float* O0 = out0 + (size_t)b * plane;
    float* O1 = out1 + (size_t)b * plane;

    int tid   = threadIdx.x;
    int wbase = tid & ~63;
    int row0  = 6 * chunk;            // first staged image row (max 504+6=510)

    // ---- stage 7 rows x 44 f4 x 3 tensors = 924 x 16B, 4 rounds ----
    // u -> tensor u/308, row (u%308)/44, c4 (u%308)%44 ; LDS dst linear in u.
    // c4<40: quarter cols; c4>=40: strip cols [0,16). q=3 has only 32 real
    // quarter f4s ([384,512)); pad slots clamp in-bounds (never read).
    #pragma unroll
    for (int J = 0; J < 4; ++J) {
        int u = J * NTHR + tid;
        if (u < NF4) {
            int t   = u / 308;
            int rem = u - t * 308;
            int rr  = rem / 44;
            int c4  = rem - rr * 44;
            int g4;
            if (c4 >= 40)   g4 = c4 - 40;                    // strip [0,16)
            else if (q < 3) g4 = 32 * q + c4;                // [128q, 128q+160)
            else            g4 = (c4 < 32) ? 96 + c4 : 127;  // [384,512) + pad
            const float* g = (t == 0 ? A : (t == 1 ? P : N))
                             + (row0 + rr) * WD + g4 * 4;
            float* l = &lds[(size_t)(J * NTHR + wbase) * 4];
            __builtin_amdgcn_global_load_lds((gp1_t)(const void*)g,
                                             (lp3_t)(void*)l, 16, 0, 0);
        }
    }
    __syncthreads();   // vmcnt drain; 8 blocks/CU hide it

    // ---- compute: one (kk, m) group per lane; lane = gi*9 + kk ----
    int NM = (q == 0) ? 22 : 21;      // m's in this quarter
    if (tid >= 9 * NM) return;
    int gi = tid / 9;
    int kk = tid - 9 * gi;
    int di = kk / 3;
    int dj = kk - 3 * di;

    int j, idx;
    if (q == 0) { j = (gi < 8) ? 0 : ((gi < 15) ? 1 : 2);
                  idx = gi - ((j == 0) ? 0 : ((j == 1) ? 8 : 15)); }
    else        { j = gi / 7; idx = gi - 7 * j; }
    int mstart = (255 * j + 64 * q + 8) / 9;   // ceil((255j+64q)/9)
    int m   = mstart + idx;
    int pj2 = 9 * m - 255 * j;                 // in [64q, 64q+64)
    int r   = chunk * RB + m;

    int cbase  = 2 * pj2 + dj - 128 * q;       // local col of k=0
    int wrapk  = NP - pj2;                     // <9 only for q=3 (pj2>=247)
    int lobase = (2 * j + di) * TCOLS + cbase;

    float minvP = 0.f, maxvP = 0.f, mindP = INFINITY, maxdP = -INFINITY;
    float minvN = 0.f, maxvN = 0.f, mindN = INFINITY, maxdN = -INFINITY;
    #pragma unroll
    for (int k = 0; k < 9; ++k) {
        int lo = lobase + 2 * k + ((k >= wrapk) ? 386 : 0);  // wrap: +2 rows, strip
        float a = lds[lo];
        float p = lds[TENF + lo];
        float n = lds[2 * TENF + lo];
        float dp = fabsf(a - p);
        float dn = fabsf(a - n);
        if (dp < mindP) { mindP = dp; minvP = p; }   // first-occurrence argmin
        if (dp > maxdP) { maxdP = dp; maxvP = p; }   // first-occurrence argmax
        if (dn < mindN) { mindN = dn; minvN = n; }
        if (dn > maxdN) { maxdN = dn; maxvN = n; }
    }
    float s0 = minvP + maxvP;
    float s1 = minvN + maxvN;

    // ---- scatter to output ----
    int l   = kk * LK + r;
    int piy = l / NP;
    int pjx = l - piy * NP;
    int y0  = 2 * piy;
    int x0  = 2 * pjx;
    bool right  = (pjx == NP - 1);
    bool bottom = (piy == NP - 1);
    int ny = bottom ? 3 : 2;

    for (int yy = 0; yy < ny; ++yy) {
        float* p0 = O0 + (size_t)(y0 + yy) * WD + x0;
        float* p1 = O1 + (size_t)(y0 + yy) * WD + x0;
        if (right) {    // cols 508,509,510 = s ; col 511 = 0
            *reinterpret_cast<float4*>(p0) = make_float4(s0, s0, s0, 0.f);
            *reinterpret_cast<float4*>(p1) = make_float4(s1, s1, s1, 0.f);
        } else {
            *reinterpret_cast<float2*>(p0) = make_float2(s0, s0);
            *reinterpret_cast<float2*>(p1) = make_float2(s1, s1);
        }
    }
    if (bottom) {       // row 511 = 0
        float* p0 = O0 + (size_t)(HD - 1) * WD + x0;
        float* p1 = O1 + (size_t)(HD - 1) * WD + x0;
        if (right) {
            *reinterpret_cast<float4*>(p0) = make_float4(0.f, 0.f, 0.f, 0.f);
            *reinterpret_cast<float4*>(p1) = make_float4(0.f, 0.f, 0.f, 0.f);
        } else {
            *reinterpret_cast<float2*>(p0) = make_float2(0.f, 0.f);
            *reinterpret_cast<float2*>(p1) = make_float2(0.f, 0.f);
        }
    }
}

extern "C" void kernel_launch(void* const* d_in, const int* in_sizes, int n_in,
                              void* d_out, int out_size, void* d_ws, size_t ws_size,
                              hipStream_t stream) {
    const float* anchor = (const float*)d_in[0];
    const float* pos    = (const float*)d_in[1];
    const float* neg    = (const float*)d_in[2];
    float* out0 = (float*)d_out;
    float* out1 = out0 + (size_t)BATCH * HD * WD;

    dc_pool_kernel<<<NWG, NTHR, 0, stream>>>(anchor, pos, neg, out0, out1);
}

// Round 12
// 37.416 us; speedup vs baseline: 1.1102x; 1.1102x over previous
//
#include <hip/hip_runtime.h>
#include <math.h>

#define HD 512
#define WD 512
#define NP 255            // patch grid = 255 x 255
#define LK 7225           // patches per kk group; 7225 = 85*85
#define BATCH 32
#define RB 85             // r's per chunk (765 ll = exactly 3 pi2-rows)
#define CH 85
#define NTHR 384          // 6 waves, ALL in staging and compute
#define ROWF 144          // parity-plane row length (h=0: 144 used; h=1: 136)
#define PLT 2016          // floats per tensor: even 7*144 + odd 7*144
#define NWG (BATCH * CH * 2)   // 5440 (div by 8 -> clean XCD swizzle)

// Semantics (reference's flat reshape (b,9,L)->(b,L,9)):
//   l = kk*7225 + r ; (di,dj) = (kk/3, kk%3) fixed within a 9-group
//   k in 0..8: ll = 9r+k -> pixel (2*(ll/255)+di, 2*(ll%255)+dj)
//   argmin/argmax |a-c| (first-occurrence), s = c[argmin]+c[argmax]
//   broadcast to 2x2 (3x3 at edges) block of patch (l/255, l%255); row/col 511 = 0.
//
// R11 = R10 with the staging-width bug fixed (h=0 needs 36 8-float chunks/row
// = cols [0,288), not 18). Design: R8 geometry (half-chunk blocks, contiguous
// 7-row fetch, XCD swizzle) + R3 parity de-interleave (even/odd col planes ->
// stride-9 reads, gcd(9,32)=1 conflict-free) + one-group-per-lane (all 6
// waves compute; lane = kk*NGM+gi -> consecutive lanes = consecutive m:
// conflict-free reads AND coalesced float2 stores).
// h=0: pj2<128 (43 m), stages cols [0,288). h=1: pj2>=128 (42 m), stages
// cols [256,512) + 16-col wrap strip; wrap bump = +289 (2 plane rows + strip).

__global__ __launch_bounds__(NTHR) void dc_pool_kernel(
    const float* __restrict__ anchor,
    const float* __restrict__ pos,
    const float* __restrict__ neg,
    float* __restrict__ out0,
    float* __restrict__ out1)
{
    __shared__ float lds[3 * PLT];   // A | P | N ; each: even[7][144] odd[7][144]

    // XCD-aware swizzle (bijective: NWG % 8 == 0); halves of a chunk adjacent.
    int bid = blockIdx.x;
    int vid = (bid & 7) * (NWG / 8) + (bid >> 3);
    int h     = vid & 1;
    int rest  = vid >> 1;
    int chunk = rest % CH;
    int b     = rest / CH;

    const size_t plane = (size_t)HD * WD;
    const float* A = anchor + (size_t)b * plane;
    const float* P = pos    + (size_t)b * plane;
    const float* N = neg    + (size_t)b * plane;
    float* O0 = out0 + (size_t)b * plane;
    float* O1 = out1 + (size_t)b * plane;

    int tid  = threadIdx.x;
    int row0 = 6 * chunk;             // first staged image row (max 510)

    // ---- stage: 32B chunk per lane -> 1 even-b128 + 1 odd-b128 ds_write ----
    // per tensor: h=0: 7 rows x 36 chunks (cols [0,288))            = 252
    //             h=1: 7 rows x 34 chunks ([256,512) + strip [0,16)) = 238
    int perRow = h ? 34 : 36;
    int perT   = 7 * perRow;
    int NC     = 3 * perT;            // 756 / 714  (<= 2*NTHR)
    #pragma unroll
    for (int J = 0; J < 2; ++J) {
        int u = J * NTHR + tid;
        if (u < NC) {
            int t   = u / perT;
            int rem = u - t * perT;
            int rr  = rem / perRow;
            int w   = rem - rr * perRow;
            int col0, ent;
            if (!h)          { col0 = 8 * w;          ent = 4 * w; }
            else if (w < 32) { col0 = 256 + 8 * w;    ent = 4 * w; }
            else             { col0 = 8 * (w - 32);   ent = 128 + 4 * (w - 32); }
            const float* g = (t == 0 ? A : (t == 1 ? P : N))
                             + (size_t)(row0 + rr) * WD + col0;
            float4 a0 = *reinterpret_cast<const float4*>(g);
            float4 a1 = *reinterpret_cast<const float4*>(g + 4);
            int e = t * PLT + rr * ROWF + ent;
            *reinterpret_cast<float4*>(&lds[e])        = make_float4(a0.x, a0.z, a1.x, a1.z);
            *reinterpret_cast<float4*>(&lds[e + 1008]) = make_float4(a0.y, a0.w, a1.y, a1.w);
        }
    }
    __syncthreads();

    // ---- compute: one (kk, gi) group per lane; lane = kk*NGM + gi ----
    int NGM   = 43 - h;               // m's in this half
    int total = 9 * NGM;              // 387 / 378
    for (int glane = tid; glane < total; glane += NTHR) {
        int kk = glane / NGM;
        int gi = glane - kk * NGM;
        int di = kk / 3;
        int dj = kk - 3 * di;

        int j, m;
        if (!h) { j = (gi < 15) ? 0 : ((gi < 29) ? 1 : 2);
                  m = gi + ((gi < 15) ? 0 : ((gi < 29) ? 14 : 28)); }
        else    { j = (gi < 14) ? 0 : ((gi < 28) ? 1 : 2);
                  m = gi + ((gi < 14) ? 15 : ((gi < 28) ? 29 : 43)); }
        int pj2 = 9 * m - 255 * j;
        int r   = chunk * RB + m;
        int rr  = 2 * j + di;

        int pb    = (dj == 1) ? 1008 : 0;   // odd plane for dj=1, else even
        int base0 = pb + rr * ROWF + pj2 - (h ? 128 : 0) + ((dj == 2) ? 1 : 0);
        int wrapk = NP - pj2;               // <9 only in h=1 (pj2>=247)

        float minvP = 0.f, maxvP = 0.f, mindP = INFINITY, maxdP = -INFINITY;
        float minvN = 0.f, maxvN = 0.f, mindN = INFINITY, maxdN = -INFINITY;
        #pragma unroll
        for (int k = 0; k < 9; ++k) {
            int lo = base0 + k + ((k >= wrapk) ? 289 : 0);  // wrap: +2 rows, strip
            float a = lds[lo];
            float p = lds[PLT + lo];
            float n = lds[2 * PLT + lo];
            float dp = fabsf(a - p);
            float dn = fabsf(a - n);
            if (dp < mindP) { mindP = dp; minvP = p; }   // first-occurrence argmin
            if (dp > maxdP) { maxdP = dp; maxvP = p; }   // first-occurrence argmax
            if (dn < mindN) { mindN = dn; minvN = n; }
            if (dn > maxdN) { maxdN = dn; maxvN = n; }
        }
        float s0 = minvP + maxvP;
        float s1 = minvN + maxvN;

        // ---- scatter to output (consecutive lanes -> consecutive float2) ----
        int l   = kk * LK + r;
        int piy = l / NP;
        int pjx = l - piy * NP;
        int y0  = 2 * piy;
        int x0  = 2 * pjx;
        bool right  = (pjx == NP - 1);
        bool bottom = (piy == NP - 1);
        int ny = bottom ? 3 : 2;

        for (int yy = 0; yy < ny; ++yy) {
            float* p0 = O0 + (size_t)(y0 + yy) * WD + x0;
            float* p1 = O1 + (size_t)(y0 + yy) * WD + x0;
            if (right) {    // cols 508,509,510 = s ; col 511 = 0
                *reinterpret_cast<float4*>(p0) = make_float4(s0, s0, s0, 0.f);
                *reinterpret_cast<float4*>(p1) = make_float4(s1, s1, s1, 0.f);
            } else {
                *reinterpret_cast<float2*>(p0) = make_float2(s0, s0);
                *reinterpret_cast<float2*>(p1) = make_float2(s1, s1);
            }
        }
        if (bottom) {       // row 511 = 0
            float* p0 = O0 + (size_t)(HD - 1) * WD + x0;
            float* p1 = O1 + (size_t)(HD - 1) * WD + x0;
            if (right) {
                *reinterpret_cast<float4*>(p0) = make_float4(0.f, 0.f, 0.f, 0.f);
                *reinterpret_cast<float4*>(p1) = make_float4(0.f, 0.f, 0.f, 0.f);
            } else {
                *reinterpret_cast<float2*>(p0) = make_float2(0.f, 0.f);
                *reinterpret_cast<float2*>(p1) = make_float2(0.f, 0.f);
            }
        }
    }
}

extern "C" void kernel_launch(void* const* d_in, const int* in_sizes, int n_in,
                              void* d_out, int out_size, void* d_ws, size_t ws_size,
                              hipStream_t stream) {
    const float* anchor = (const float*)d_in[0];
    const float* pos    = (const float*)d_in[1];
    const float* neg    = (const float*)d_in[2];
    float* out0 = (float*)d_out;
    float* out1 = out0 + (size_t)BATCH * HD * WD;

    dc_pool_kernel<<<NWG, NTHR, 0, stream>>>(anchor, pos, neg, out0, out1);
}